// Round 2
// baseline (394.067 us; speedup 1.0000x reference)
//
#include <hip/hip_runtime.h>
#include <stdint.h>

#define N_ROWS 16384
#define DIM    512

typedef float v4f __attribute__((ext_vector_type(4)));
typedef int   v4i __attribute__((ext_vector_type(4)));
typedef int   v8i __attribute__((ext_vector_type(8)));
typedef unsigned long long u64;
typedef unsigned char u8;

// Monotonic float -> sortable u32 key
__device__ __forceinline__ unsigned fkey(float f) {
    unsigned u = __float_as_uint(f);
    return (u & 0x80000000u) ? ~u : (u | 0x80000000u);
}

// Async global->LDS, 16B per lane. LDS dest = wave-uniform base + lane*16.
__device__ __forceinline__ void gload_lds16(const void* g, void* l) {
    __builtin_amdgcn_global_load_lds(
        (const __attribute__((address_space(1))) unsigned int*)g,
        (__attribute__((address_space(3))) unsigned int*)l,
        16, 0, 0);
}

// ---------------- kernel 1: fp32 -> fp8 e4m3 convert (+ table zero-init) ----------------
// HW RNE; x ~ N(0,1), e4m3 max 448 -> no saturation. Validated (absmax 0.0).
__global__ __launch_bounds__(256)
void convert_fp8_kernel(const float* __restrict__ x, unsigned* __restrict__ x8,
                        u64* __restrict__ table) {
    int tid    = blockIdx.x * blockDim.x + threadIdx.x;
    int stride = gridDim.x * blockDim.x;
    if (tid < N_ROWS) table[tid] = 0;
    const float4* x4 = (const float4*)x;
    const int n4 = (N_ROWS * DIM) / 4;
    for (int i = tid; i < n4; i += stride) {
        float4 v = x4[i];
        int b = __builtin_amdgcn_cvt_pk_fp8_f32(v.x, v.y, 0, false);   // bytes 0,1
        b     = __builtin_amdgcn_cvt_pk_fp8_f32(v.z, v.w, b, true);    // bytes 2,3
        x8[i] = (unsigned)b;
    }
}

// ---------------- kernel 2: symmetric tiled fp8 GEMM + fused argmax ----------------
// r10 = proven r8 structure (128^2 tile, 4 waves, BK=128, 2 barriers/round,
// triangle fold) with the MFMA swapped to the MX-scaled K=128 instruction:
//   mfma_scale_f32_16x16x128_f8f6f4, fmt A/B = fp8 e4m3, all block scales =
//   e8m0 127 (= 1.0) -> numerically IDENTICAL to non-scaled fp8, but the
//   scaled pipe runs ~4.66 PF vs ~2.1 PF (m21/m148: same port on the m97
//   structure gave +1.64x). 16 MFMA/round instead of 64; schedule untouched
//   (r9's phase-split port regressed 174->233 us -- m196's coarse-split trap).
// LDS layout per matrix (16 KB, swizzle at 16-fp8 chunks): tile = 128 rows
// x 128 k-bytes = 128 x 8 chunks. Slot (row, sk) holds chunk kc = sk ^ (row&7).
//  * staging lane L: row=L>>3, sk=L&7 -> src kc=(L&7)^(row&7); 8-lane groups
//    load full 128 B rows -> coalesced.
//  * frag read (quad q, lane15 l): K=128 operand = 32 B = chunks {2q, 2q+1}
//    of row rf*16+l -> addr = row*128 + ((2q+j)^(l&7))*16, j=0,1; two
//    ds_read_b128. 16-lane phase: 8 slots x 2 rows -> 2-way aliasing = free
//    (m136). rf*16 = 0 mod 8 -> xor term is lane-only.
__global__ __launch_bounds__(256)
void argmax_dots_kernel(const u8* __restrict__ xb, u64* __restrict__ table) {
    __shared__ __attribute__((aligned(16))) u8 ldsA[128 * 128];  // 16 KB
    __shared__ __attribute__((aligned(16))) u8 ldsB[128 * 128];  // 16 KB

    const int u = blockIdx.x >> 6;
    const int p = blockIdx.x & 63;
    const int rT = (u <= p) ? (127 - p) : p;
    const int cT = (u <= p) ? (127 - u) : (u - 1);

    const int t      = threadIdx.x;
    const int lane   = t & 63;
    const int wave   = t >> 6;
    const int lane15 = lane & 15;
    const int quad   = lane >> 4;
    const int rh = wave >> 1;               // row half of the 128x128 tile
    const int ch = wave & 1;                // col half

    const int rowBase = rT * 128;
    const int colBase = cT * 128;

    // Staging sources: 4 issues per matrix per round, coalesced row-major.
    const u8* gA[4];
    const u8* gB[4];
#pragma unroll
    for (int j = 0; j < 4; ++j) {
        const int L   = j * 256 + t;
        const int row = L >> 3;
        const int kc  = (L & 7) ^ (row & 7);       // swizzled source chunk
        gA[j] = xb + (size_t)(rowBase + row) * DIM + kc * 16;
        gB[j] = xb + (size_t)(colBase + row) * DIM + kc * 16;
    }
    const int dstOff = wave * 1024;         // + j*4096 per issue (bytes)

    // Per-lane frag addresses: row base + rf*2048 + chunk-xor (lane-only)
    const int aBase = (rh * 64 + lane15) * 128;
    const int bBase = (ch * 64 + lane15) * 128;
    const int xc0 = ((2 * quad + 0) ^ (lane15 & 7)) << 4;
    const int xc1 = ((2 * quad + 1) ^ (lane15 & 7)) << 4;

    v4f acc[4][4];
#pragma unroll
    for (int rf = 0; rf < 4; ++rf)
#pragma unroll
        for (int cf = 0; cf < 4; ++cf) {
            v4f z = {0.f, 0.f, 0.f, 0.f};
            acc[rf][cf] = z;
        }

    union V8 { v8i v; v4i h[2]; };
    const int S1 = 0x7F7F7F7F;              // e8m0 127 = scale 1.0, all bytes

#pragma unroll
    for (int k = 0; k < 4; ++k) {           // 4 K-rounds of BK=128
        const int kk = k * 128;             // byte offset within a row
#pragma unroll
        for (int j = 0; j < 4; ++j) {
            gload_lds16(gA[j] + kk, (char*)ldsA + j * 4096 + dstOff);
            gload_lds16(gB[j] + kk, (char*)ldsB + j * 4096 + dstOff);
        }
        __syncthreads();                    // drains vmcnt; loads visible

        v8i a8[4], b8[4];
#pragma unroll
        for (int rf = 0; rf < 4; ++rf) {
            union V8 ua;
            ua.h[0] = *(const v4i*)(ldsA + aBase + rf * 2048 + xc0);
            ua.h[1] = *(const v4i*)(ldsA + aBase + rf * 2048 + xc1);
            a8[rf] = ua.v;
        }
#pragma unroll
        for (int cf = 0; cf < 4; ++cf) {
            union V8 ub;
            ub.h[0] = *(const v4i*)(ldsB + bBase + cf * 2048 + xc0);
            ub.h[1] = *(const v4i*)(ldsB + bBase + cf * 2048 + xc1);
            b8[cf] = ub.v;
        }
#pragma unroll
        for (int rf = 0; rf < 4; ++rf)
#pragma unroll
            for (int cf = 0; cf < 4; ++cf)
                acc[rf][cf] = __builtin_amdgcn_mfma_scale_f32_16x16x128_f8f6f4(
                    a8[rf], b8[cf], acc[rf][cf],
                    0, 0,                   // cbsz=fp8 e4m3, blgp=fp8 e4m3
                    0, S1, 0, S1);          // scaleA/B = 1.0 (opsel 0)
        __syncthreads();                    // protect LDS from next round's writes
    }

    // ---- epilogue: row-side argmax (C/D layout: col=lane15+16*cf, row=quad*4+e) ----
    const int colLane = colBase + ch * 64 + lane15;
#pragma unroll
    for (int rf = 0; rf < 4; ++rf) {
#pragma unroll
        for (int e = 0; e < 4; ++e) {
            const int row = rowBase + rh * 64 + rf * 16 + quad * 4 + e;
            float bv = -3.0e38f;
            int   bc = 0;
#pragma unroll
            for (int cf = 0; cf < 4; ++cf) {
                const float v = acc[rf][cf][e];
                const int col = colLane + cf * 16;
                if (v > bv && col != row) { bv = v; bc = col; }
            }
            u64 packed = ((u64)fkey(bv) << 32) | (unsigned)(~bc);  // ~col: ties->lowest idx
#pragma unroll
            for (int m = 1; m < 16; m <<= 1) {
                u64 o = __shfl_xor(packed, m, 64);
                if (o > packed) packed = o;
            }
            if (lane15 == 0) atomicMax(&table[row], packed);
        }
    }

    // ---- epilogue: col-side (transposed) argmax for off-diagonal tiles ----
    if (rT != cT) {
#pragma unroll
        for (int cf = 0; cf < 4; ++cf) {
            const int col = colLane + cf * 16;
            float bv = -3.0e38f;
            int   br_ = 0;
#pragma unroll
            for (int rf = 0; rf < 4; ++rf)
#pragma unroll
                for (int e = 0; e < 4; ++e) {
                    const float v = acc[rf][cf][e];
                    const int row = rowBase + rh * 64 + rf * 16 + quad * 4 + e;
                    if (v > bv) { bv = v; br_ = row; }
                }
            u64 packed = ((u64)fkey(bv) << 32) | (unsigned)(~br_);
            u64 o = __shfl_xor(packed, 16, 64); if (o > packed) packed = o;
            o     = __shfl_xor(packed, 32, 64); if (o > packed) packed = o;
            if (quad == 0) atomicMax(&table[col], packed);
        }
    }
}

// ---------------- kernel 3: rho + loss epilogue (fp32 exact) ----------------
__global__ __launch_bounds__(256)
void rho_loss_kernel(const float* __restrict__ x, const u64* __restrict__ table,
                     float* __restrict__ out) {
    const int lane = threadIdx.x & 63;
    const int wave = threadIdx.x >> 6;
    const int waveGlobal = blockIdx.x * 4 + wave;   // 2048 waves

    float local = 0.f;
    for (int r8 = 0; r8 < 8; ++r8) {
        const int row = waveGlobal * 8 + r8;
        const u64 packed = table[row];
        const int nb = (int)(~(unsigned)(packed & 0xFFFFFFFFu));

        const float4* xr = (const float4*)(x + (size_t)row * DIM);
        const float4* xn = (const float4*)(x + (size_t)nb  * DIM);
        float s = 0.f;
#pragma unroll
        for (int tt = 0; tt < 2; ++tt) {
            float4 a = xr[lane * 2 + tt];
            float4 b = xn[lane * 2 + tt];
            float d0 = a.x - b.x + 1e-6f;
            float d1 = a.y - b.y + 1e-6f;
            float d2 = a.z - b.z + 1e-6f;
            float d3 = a.w - b.w + 1e-6f;
            s += d0 * d0 + d1 * d1 + d2 * d2 + d3 * d3;
        }
#pragma unroll
        for (int m = 1; m < 64; m <<= 1) s += __shfl_xor(s, m, 64);

        if (lane == 0) {
            float rho = sqrtf(s);
            local += logf(rho + 1e-8f);
        }
    }
    if (lane == 0) atomicAdd(out, -local * (1.0f / 16384.0f));
}

extern "C" void kernel_launch(void* const* d_in, const int* in_sizes, int n_in,
                              void* d_out, int out_size, void* d_ws, size_t ws_size,
                              hipStream_t stream) {
    const float* x = (const float*)d_in[0];

    // Workspace: [0, 8 MiB) fp8 x; then 16384 x u64 argmax table.
    u8*    xb    = (u8*)d_ws;
    u64*   table = (u64*)((char*)d_ws + (size_t)N_ROWS * DIM);
    float* out   = (float*)d_out;

    hipMemsetAsync(out, 0, sizeof(float), stream);

    convert_fp8_kernel<<<2048, 256, 0, stream>>>(x, (unsigned*)xb, table);
    argmax_dots_kernel<<<8256, 256, 0, stream>>>(xb, table);
    rho_loss_kernel<<<512, 256, 0, stream>>>(x, table, out);
}

// Round 3
// 285.319 us; speedup vs baseline: 1.3811x; 1.3811x over previous
//
#include <hip/hip_runtime.h>
#include <stdint.h>

#define N_ROWS 16384
#define DIM    512

typedef float v4f __attribute__((ext_vector_type(4)));
typedef unsigned long long u64;
typedef unsigned char u8;

// Monotonic float -> sortable u32 key
__device__ __forceinline__ unsigned fkey(float f) {
    unsigned u = __float_as_uint(f);
    return (u & 0x80000000u) ? ~u : (u | 0x80000000u);
}

// Async global->LDS, 16B per lane. LDS dest = wave-uniform base + lane*16.
__device__ __forceinline__ void gload_lds16(const void* g, void* l) {
    __builtin_amdgcn_global_load_lds(
        (const __attribute__((address_space(1))) unsigned int*)g,
        (__attribute__((address_space(3))) unsigned int*)l,
        16, 0, 0);
}

// ---------------- kernel 1: fp32 -> fp8 e4m3 convert (+ table & out zero-init) ----------------
// HW RNE; x ~ N(0,1), e4m3 max 448 -> no saturation. Validated (absmax 0.0).
// r11: also zeroes the scalar output here (drops the hipMemsetAsync dispatch).
__global__ __launch_bounds__(256)
void convert_fp8_kernel(const float* __restrict__ x, unsigned* __restrict__ x8,
                        u64* __restrict__ table, float* __restrict__ out) {
    int tid    = blockIdx.x * blockDim.x + threadIdx.x;
    int stride = gridDim.x * blockDim.x;
    if (tid == 0) *out = 0.f;
    if (tid < N_ROWS) table[tid] = 0;
    const float4* x4 = (const float4*)x;
    const int n4 = (N_ROWS * DIM) / 4;
    for (int i = tid; i < n4; i += stride) {
        float4 v = x4[i];
        int b = __builtin_amdgcn_cvt_pk_fp8_f32(v.x, v.y, 0, false);   // bytes 0,1
        b     = __builtin_amdgcn_cvt_pk_fp8_f32(v.z, v.w, b, true);    // bytes 2,3
        x8[i] = (unsigned)b;
    }
}

// ---------------- kernel 2: symmetric tiled fp8 GEMM + fused argmax ----------------
// PROVEN structure (174 us, MfmaUtil 33, the best of 3 measured variants):
// 128^2 tile, 4 waves, BK=128 fp8, 2 barriers/round, triangle fold.
// r9 (8-wave phase-split, 256^2) regressed to 233 us: coarse phase split
// without the fine interleave + 1 block/CU occupancy (m196 trap).
// r10 (MX-scaled K=128 MFMA) regressed to 316 us: MFMA pipe itself hit its
// 28 us floor (MfmaUtil 8.8% x 316), but +64 live VGPRs (v8i operands)
// collapsed occupancy 31.8->11.5% and the barrier drain became the naked
// critical path. This structure's non-MFMA time (~116 us) only stays hidden
// with >=2.5 resident blocks/CU and a long MFMA phase. Both documented
// escape routes refuted here -> keep the 39%-of-pipe ceiling kernel.
//
// Triangle-fold schedule: b = u*64 + p; u<=p -> (127-p,127-u), else (p,u-1).
// LDS layout per matrix (16 KB, swizzle at 16-fp8 chunks): tile = 128 rows
// x 128 k-bytes = 128 x 8 chunks. Slot (row, sk) holds chunk kc = sk ^ (row&7).
//  * staging lane L: row=L>>3, sk=L&7 -> src kc=(L&7)^(row&7); 8-lane groups
//    load full 128 B rows -> coalesced.
//  * frag read (k-step s, quad q, lane15 l): wants 8 B at kc=2s+(q>>1), half
//    q&1 of row rf*16+l -> addr = row*128 + ((2s+(q>>1))^(l&7))*16 + (q&1)*8.
//    ds_read_b64 natural 16-lane phases: banks (c^(l&7))*4+2(q&1) -> 2-way
//    aliasing = free (m136).
__global__ __launch_bounds__(256)
void argmax_dots_kernel(const u8* __restrict__ xb, u64* __restrict__ table) {
    __shared__ __attribute__((aligned(16))) u8 ldsA[128 * 128];  // 16 KB
    __shared__ __attribute__((aligned(16))) u8 ldsB[128 * 128];  // 16 KB

    const int u = blockIdx.x >> 6;
    const int p = blockIdx.x & 63;
    const int rT = (u <= p) ? (127 - p) : p;
    const int cT = (u <= p) ? (127 - u) : (u - 1);

    const int t      = threadIdx.x;
    const int lane   = t & 63;
    const int wave   = t >> 6;
    const int lane15 = lane & 15;
    const int quad   = lane >> 4;
    const int rh = wave >> 1;               // row half of the 128x128 tile
    const int ch = wave & 1;                // col half

    const int rowBase = rT * 128;
    const int colBase = cT * 128;

    // Staging sources: 4 issues per matrix per round, coalesced row-major.
    const u8* gA[4];
    const u8* gB[4];
#pragma unroll
    for (int j = 0; j < 4; ++j) {
        const int L   = j * 256 + t;
        const int row = L >> 3;
        const int kc  = (L & 7) ^ (row & 7);       // swizzled source chunk
        gA[j] = xb + (size_t)(rowBase + row) * DIM + kc * 16;
        gB[j] = xb + (size_t)(colBase + row) * DIM + kc * 16;
    }
    const int dstOff = wave * 1024;         // + j*4096 per issue (bytes)

    // Per-lane frag address pieces: addr = base + rf*2048 + xorK[s]
    const int aBase = (rh * 64 + lane15) * 128 + (quad & 1) * 8;
    const int bBase = (ch * 64 + lane15) * 128 + (quad & 1) * 8;
    int xorK[4];
#pragma unroll
    for (int s = 0; s < 4; ++s)
        xorK[s] = ((2 * s + (quad >> 1)) ^ (lane15 & 7)) << 4;

    v4f acc[4][4];
#pragma unroll
    for (int rf = 0; rf < 4; ++rf)
#pragma unroll
        for (int cf = 0; cf < 4; ++cf) {
            v4f z = {0.f, 0.f, 0.f, 0.f};
            acc[rf][cf] = z;
        }

#pragma unroll
    for (int k = 0; k < 4; ++k) {           // 4 K-rounds of BK=128
        const int kk = k * 128;             // byte offset within a row
#pragma unroll
        for (int j = 0; j < 4; ++j) {
            gload_lds16(gA[j] + kk, (char*)ldsA + j * 4096 + dstOff);
            gload_lds16(gB[j] + kk, (char*)ldsB + j * 4096 + dstOff);
        }
        __syncthreads();                    // drains vmcnt; loads visible

#pragma unroll
        for (int s = 0; s < 4; ++s) {       // 4 k-steps of 32 fp8
            const int xs = xorK[s];
            long a8[4], b8[4];
#pragma unroll
            for (int rf = 0; rf < 4; ++rf)
                a8[rf] = *(const long*)(ldsA + aBase + rf * 2048 + xs);
#pragma unroll
            for (int cf = 0; cf < 4; ++cf)
                b8[cf] = *(const long*)(ldsB + bBase + cf * 2048 + xs);
#pragma unroll
            for (int rf = 0; rf < 4; ++rf)
#pragma unroll
                for (int cf = 0; cf < 4; ++cf)
                    acc[rf][cf] = __builtin_amdgcn_mfma_f32_16x16x32_fp8_fp8(
                        a8[rf], b8[cf], acc[rf][cf], 0, 0, 0);
        }
        __syncthreads();                    // protect LDS from next round's writes
    }

    // ---- epilogue: row-side argmax (C/D layout: col=lane15+16*cf, row=quad*4+e) ----
    const int colLane = colBase + ch * 64 + lane15;
#pragma unroll
    for (int rf = 0; rf < 4; ++rf) {
#pragma unroll
        for (int e = 0; e < 4; ++e) {
            const int row = rowBase + rh * 64 + rf * 16 + quad * 4 + e;
            float bv = -3.0e38f;
            int   bc = 0;
#pragma unroll
            for (int cf = 0; cf < 4; ++cf) {
                const float v = acc[rf][cf][e];
                const int col = colLane + cf * 16;
                if (v > bv && col != row) { bv = v; bc = col; }
            }
            u64 packed = ((u64)fkey(bv) << 32) | (unsigned)(~bc);  // ~col: ties->lowest idx
#pragma unroll
            for (int m = 1; m < 16; m <<= 1) {
                u64 o = __shfl_xor(packed, m, 64);
                if (o > packed) packed = o;
            }
            if (lane15 == 0) atomicMax(&table[row], packed);
        }
    }

    // ---- epilogue: col-side (transposed) argmax for off-diagonal tiles ----
    if (rT != cT) {
#pragma unroll
        for (int cf = 0; cf < 4; ++cf) {
            const int col = colLane + cf * 16;
            float bv = -3.0e38f;
            int   br_ = 0;
#pragma unroll
            for (int rf = 0; rf < 4; ++rf)
#pragma unroll
                for (int e = 0; e < 4; ++e) {
                    const float v = acc[rf][cf][e];
                    const int row = rowBase + rh * 64 + rf * 16 + quad * 4 + e;
                    if (v > bv) { bv = v; br_ = row; }
                }
            u64 packed = ((u64)fkey(bv) << 32) | (unsigned)(~br_);
            u64 o = __shfl_xor(packed, 16, 64); if (o > packed) packed = o;
            o     = __shfl_xor(packed, 32, 64); if (o > packed) packed = o;
            if (quad == 0) atomicMax(&table[col], packed);
        }
    }
}

// ---------------- kernel 3: rho + loss epilogue (fp32 exact) ----------------
// r11: 1024 blocks x 4 rows/wave (was 512 x 8) -- doubles wave-level
// parallelism for this latency-bound loop (dependent table->row loads +
// 6-level shuffle chain per row). Per-row numerics identical.
__global__ __launch_bounds__(256)
void rho_loss_kernel(const float* __restrict__ x, const u64* __restrict__ table,
                     float* __restrict__ out) {
    const int lane = threadIdx.x & 63;
    const int wave = threadIdx.x >> 6;
    const int waveGlobal = blockIdx.x * 4 + wave;   // 4096 waves

    float local = 0.f;
    for (int r4 = 0; r4 < 4; ++r4) {
        const int row = waveGlobal * 4 + r4;
        const u64 packed = table[row];
        const int nb = (int)(~(unsigned)(packed & 0xFFFFFFFFu));

        const float4* xr = (const float4*)(x + (size_t)row * DIM);
        const float4* xn = (const float4*)(x + (size_t)nb  * DIM);
        float s = 0.f;
#pragma unroll
        for (int tt = 0; tt < 2; ++tt) {
            float4 a = xr[lane * 2 + tt];
            float4 b = xn[lane * 2 + tt];
            float d0 = a.x - b.x + 1e-6f;
            float d1 = a.y - b.y + 1e-6f;
            float d2 = a.z - b.z + 1e-6f;
            float d3 = a.w - b.w + 1e-6f;
            s += d0 * d0 + d1 * d1 + d2 * d2 + d3 * d3;
        }
#pragma unroll
        for (int m = 1; m < 64; m <<= 1) s += __shfl_xor(s, m, 64);

        if (lane == 0) {
            float rho = sqrtf(s);
            local += logf(rho + 1e-8f);
        }
    }
    if (lane == 0) atomicAdd(out, -local * (1.0f / 16384.0f));
}

extern "C" void kernel_launch(void* const* d_in, const int* in_sizes, int n_in,
                              void* d_out, int out_size, void* d_ws, size_t ws_size,
                              hipStream_t stream) {
    const float* x = (const float*)d_in[0];

    // Workspace: [0, 8 MiB) fp8 x; then 16384 x u64 argmax table.
    u8*    xb    = (u8*)d_ws;
    u64*   table = (u64*)((char*)d_ws + (size_t)N_ROWS * DIM);
    float* out   = (float*)d_out;

    convert_fp8_kernel<<<2048, 256, 0, stream>>>(x, (unsigned*)xb, table, out);
    argmax_dots_kernel<<<8256, 256, 0, stream>>>(xb, table);
    rho_loss_kernel<<<1024, 256, 0, stream>>>(x, table, out);
}